// Round 1
// baseline (1391.562 us; speedup 1.0000x reference)
//
#include <hip/hip_runtime.h>
#include <hip/hip_bf16.h>
#include <math.h>

// Problem dims (fixed by reference): G=8, E=8, C=512, H=1024, F=4096
#define GG 8
#define EE 8
#define CC 512
#define HH 1024
#define FF 4096

typedef __attribute__((ext_vector_type(8))) short bf16x8;   // 8 bf16 = 4 VGPRs
typedef __attribute__((ext_vector_type(4))) float f32x4;

__device__ __forceinline__ unsigned short f2bf(float f) {
  unsigned int u = __float_as_uint(f);
  u += 0x7FFFu + ((u >> 16) & 1u);   // RTNE
  return (unsigned short)(u >> 16);
}

__device__ __forceinline__ void gload_lds16(const void* g, void* l) {
  // async global->LDS, 16B/lane; LDS dest is wave-uniform base + lane*16
  __builtin_amdgcn_global_load_lds((__attribute__((address_space(1))) void*)g,
                                   (__attribute__((address_space(3))) void*)l,
                                   16, 0, 0);
}

// ---------------- fp32 -> bf16 straight conversion (vectorized) ----------------
__global__ void convert_bf16_kernel(const float4* __restrict__ in,
                                    ushort4* __restrict__ out) {
  const int i = blockIdx.x * blockDim.x + threadIdx.x;
  const float4 v = in[i];
  ushort4 o;
  o.x = f2bf(v.x); o.y = f2bf(v.y); o.z = f2bf(v.z); o.w = f2bf(v.w);
  out[i] = o;
}

// ---------------- fp32 (R x C) -> bf16 (C x R) transpose, per blockIdx.z slab ----------------
__global__ void transpose_bf16(const float* __restrict__ in,
                               unsigned short* __restrict__ out,
                               int R, int C) {
  __shared__ float tile[64][65];                 // +1 pad breaks bank conflicts
  const long ebase = (long)blockIdx.z * R * C;
  const int r0 = blockIdx.y * 64, c0 = blockIdx.x * 64;
  const int t = threadIdx.x;
  const int lr = t >> 4;            // 0..15
  const int lc = (t & 15) * 4;      // 0,4,...,60
#pragma unroll
  for (int p = 0; p < 4; ++p) {
    const int r = lr + p * 16;
    const float4 v = *(const float4*)(in + ebase + (long)(r0 + r) * C + c0 + lc);
    tile[r][lc + 0] = v.x; tile[r][lc + 1] = v.y;
    tile[r][lc + 2] = v.z; tile[r][lc + 3] = v.w;
  }
  __syncthreads();
#pragma unroll
  for (int p = 0; p < 4; ++p) {
    const int c = lr + p * 16;      // output row (original col)
    ushort4 o;
    o.x = f2bf(tile[lc + 0][c]);
    o.y = f2bf(tile[lc + 1][c]);
    o.z = f2bf(tile[lc + 2][c]);
    o.w = f2bf(tile[lc + 3][c]);
    *(ushort4*)(out + ebase + (long)(c0 + c) * R + r0 + lc) = o;
  }
}

// ---------------- bf16 GEMM: (rows x K) @ (N x K)^T, 128x128 tile, BK=32 ----------------
// A rows are grouped per z = g*E+e in 512-row chunks. Bt/bias are per-expert (e = z&7).
// GELU=1: exact gelu epilogue, bf16 store. GELU=0: fp32 store.
template <int GELU>
__global__ __launch_bounds__(256, 2)
void ffn_gemm(const unsigned short* __restrict__ A,   // (64*512) x K bf16
              const unsigned short* __restrict__ Bt,  // E x N x K bf16
              const float* __restrict__ bias,         // E x N fp32
              void* __restrict__ Out,                 // (64*512) x N
              int K, int N) {
  __shared__ unsigned short As[128 * 32];
  __shared__ unsigned short Bs[128 * 32];

  const int z = blockIdx.z;                  // g*8 + e
  const int e = z & 7;
  const long mBase = (long)z * 512 + blockIdx.y * 128;
  const int nBase = blockIdx.x * 128;

  const unsigned short* Ab = A + mBase * K;
  const unsigned short* Bb = Bt + ((long)e * N + nBase) * K;

  const int tid = threadIdx.x;
  const int lane = tid & 63;
  const int wave = tid >> 6;
  const int wm = wave & 1, wn = wave >> 1;   // 2x2 waves, each 64x64
  const int q = lane >> 4, mn = lane & 15;
  const int srow = lane >> 2, sb = lane & 3; // staging: 16 rows x 4 k-blocks per chunk

  f32x4 acc[4][4] = {};

  for (int k0 = 0; k0 < K; k0 += 32) {
    __syncthreads();
    // stage A and B tiles (128x32 each), 8 chunks of 1KB each, swizzled k-blocks:
    // LDS physical slot (row, b) holds global k-block (b ^ ((row>>1)&3))
#pragma unroll
    for (int j = 0; j < 2; ++j) {
      const int ca = wave + j * 4;           // chunk 0..7
      const int row = ca * 16 + srow;        // tile row 0..127
      const int kb = (sb ^ ((row >> 1) & 3)) * 8;
      gload_lds16(Ab + (long)row * K + k0 + kb, &As[ca * 512 + lane * 8]);
      gload_lds16(Bb + (long)row * K + k0 + kb, &Bs[ca * 512 + lane * 8]);
    }
    __syncthreads();

    bf16x8 af[4], bfr[4];
#pragma unroll
    for (int t = 0; t < 4; ++t) {
      const int m = wm * 64 + t * 16 + mn;
      af[t] = *(const bf16x8*)&As[m * 32 + ((q ^ ((m >> 1) & 3)) * 8)];
      const int n = wn * 64 + t * 16 + mn;
      bfr[t] = *(const bf16x8*)&Bs[n * 32 + ((q ^ ((n >> 1) & 3)) * 8)];
    }
#pragma unroll
    for (int mt = 0; mt < 4; ++mt)
#pragma unroll
      for (int nt = 0; nt < 4; ++nt)
        acc[mt][nt] = __builtin_amdgcn_mfma_f32_16x16x32_bf16(
            af[mt], bfr[nt], acc[mt][nt], 0, 0, 0);
  }

  // epilogue: C/D layout col = lane&15, row = (lane>>4)*4 + r  [m89/m91-verified]
#pragma unroll
  for (int nt = 0; nt < 4; ++nt) {
    const int n = nBase + wn * 64 + nt * 16 + mn;
    const float bv = bias[(long)e * N + n];
#pragma unroll
    for (int mt = 0; mt < 4; ++mt) {
#pragma unroll
      for (int r = 0; r < 4; ++r) {
        const long m = mBase + wm * 64 + mt * 16 + q * 4 + r;
        float v = acc[mt][nt][r] + bv;
        if (GELU) {
          v = 0.5f * v * (1.0f + erff(v * 0.70710678118654752f));
          ((unsigned short*)Out)[m * N + n] = f2bf(v);
        } else {
          ((float*)Out)[m * N + n] = v;
        }
      }
    }
  }
}

extern "C" void kernel_launch(void* const* d_in, const int* in_sizes, int n_in,
                              void* d_out, int out_size, void* d_ws, size_t ws_size,
                              hipStream_t stream) {
  const float* x  = (const float*)d_in[0];  // (G,E,C,H)
  const float* wi = (const float*)d_in[1];  // (E,H,F)
  const float* bi = (const float*)d_in[2];  // (E,F)
  const float* wo = (const float*)d_in[3];  // (E,F,H)
  const float* bo = (const float*)d_in[4];  // (E,H)
  float* out = (float*)d_out;               // (G,E,C,H) fp32

  // workspace layout (stream-ordered reuse of wt):
  //   xb: bf16 inputs            64 MiB @ 0
  //   yb: bf16 gelu intermediate 256 MiB @ 64 MiB
  //   wt: bf16 transposed weight 64 MiB @ 320 MiB (wi_t then wo_t)
  char* ws = (char*)d_ws;
  unsigned short* xb = (unsigned short*)ws;
  unsigned short* yb = (unsigned short*)(ws + (size_t)64 * 1024 * 1024);
  unsigned short* wt = (unsigned short*)(ws + (size_t)320 * 1024 * 1024);

  // 1) inputs fp32 -> bf16 (33,554,432 elems / 4 per thread / 256 per block)
  convert_bf16_kernel<<<32768, 256, 0, stream>>>((const float4*)x, (ushort4*)xb);

  // 2) wi (E,H,F) -> wi_t (E,F,H) bf16
  transpose_bf16<<<dim3(FF / 64, HH / 64, EE), 256, 0, stream>>>(wi, wt, HH, FF);

  // 3) GEMM1 + exact GELU: yb = gelu(xb @ wi_e + bi)  [K=1024, N=4096]
  ffn_gemm<1><<<dim3(FF / 128, 4, GG * EE), 256, 0, stream>>>(xb, wt, bi, yb, HH, FF);

  // 4) wo (E,F,H) -> wo_t (E,H,F) bf16 (overwrites wt; same stream => ordered)
  transpose_bf16<<<dim3(HH / 64, FF / 64, EE), 256, 0, stream>>>(wo, wt, FF, HH);

  // 5) GEMM2: out = yb @ wo_e + bo  [K=4096, N=1024], fp32 store
  ffn_gemm<0><<<dim3(HH / 128, 4, GG * EE), 256, 0, stream>>>(yb, wt, bo, out, FF, HH);
}

// Round 2
// 1196.231 us; speedup vs baseline: 1.1633x; 1.1633x over previous
//
#include <hip/hip_runtime.h>
#include <hip/hip_bf16.h>
#include <math.h>

// Problem dims (fixed by reference): G=8, E=8, C=512, H=1024, F=4096
#define GG 8
#define EE 8
#define CC 512
#define HH 1024
#define FF 4096

typedef __attribute__((ext_vector_type(8))) short bf16x8;   // 8 bf16 = 4 VGPRs
typedef __attribute__((ext_vector_type(4))) float f32x4;

__device__ __forceinline__ unsigned short f2bf(float f) {
  unsigned int u = __float_as_uint(f);
  u += 0x7FFFu + ((u >> 16) & 1u);   // RTNE
  return (unsigned short)(u >> 16);
}

__device__ __forceinline__ void gload_lds16(const void* g, void* l) {
  // async global->LDS, 16B/lane; LDS dest is wave-uniform base + lane*16
  __builtin_amdgcn_global_load_lds((__attribute__((address_space(1))) void*)g,
                                   (__attribute__((address_space(3))) void*)l,
                                   16, 0, 0);
}

// ---------------- fp32 -> bf16 straight conversion (vectorized) ----------------
__global__ void convert_bf16_kernel(const float4* __restrict__ in,
                                    ushort4* __restrict__ out) {
  const int i = blockIdx.x * blockDim.x + threadIdx.x;
  const float4 v = in[i];
  ushort4 o;
  o.x = f2bf(v.x); o.y = f2bf(v.y); o.z = f2bf(v.z); o.w = f2bf(v.w);
  out[i] = o;
}

// ---------------- fp32 (R x C) -> bf16 (C x R) transpose, per blockIdx.z slab ----------------
__global__ void transpose_bf16(const float* __restrict__ in,
                               unsigned short* __restrict__ out,
                               int R, int C) {
  __shared__ float tile[64][65];                 // +1 pad breaks bank conflicts
  const long ebase = (long)blockIdx.z * R * C;
  const int r0 = blockIdx.y * 64, c0 = blockIdx.x * 64;
  const int t = threadIdx.x;
  const int lr = t >> 4;            // 0..15
  const int lc = (t & 15) * 4;      // 0,4,...,60
#pragma unroll
  for (int p = 0; p < 4; ++p) {
    const int r = lr + p * 16;
    const float4 v = *(const float4*)(in + ebase + (long)(r0 + r) * C + c0 + lc);
    tile[r][lc + 0] = v.x; tile[r][lc + 1] = v.y;
    tile[r][lc + 2] = v.z; tile[r][lc + 3] = v.w;
  }
  __syncthreads();
#pragma unroll
  for (int p = 0; p < 4; ++p) {
    const int c = lr + p * 16;      // output row (original col)
    ushort4 o;
    o.x = f2bf(tile[lc + 0][c]);
    o.y = f2bf(tile[lc + 1][c]);
    o.z = f2bf(tile[lc + 2][c]);
    o.w = f2bf(tile[lc + 3][c]);
    *(ushort4*)(out + ebase + (long)(c0 + c) * R + r0 + lc) = o;
  }
}

// ---------------- bf16 GEMM: (rows x K) @ (N x K)^T, 128x128 tile, BK=32 ----------------
// blockIdx.z encodes (g,e) as z = e*8 + g  =>  consecutive blocks share the same
// expert's weight panel B_e (8 MiB) -> L2/LLC-resident during that expert's window.
// A rows for (g,e) live at linear slab (g*8+e)*512 (memory layout is (G,E,C,H)).
// GELU=1: exact gelu epilogue, bf16 store. GELU=0: fp32 store.
template <int GELU>
__global__ __launch_bounds__(256, 2)
void ffn_gemm(const unsigned short* __restrict__ A,   // (64*512) x K bf16
              const unsigned short* __restrict__ Bt,  // E x N x K bf16
              const float* __restrict__ bias,         // E x N fp32
              void* __restrict__ Out,                 // (64*512) x N
              int K, int N) {
  __shared__ unsigned short As[128 * 32];
  __shared__ unsigned short Bs[128 * 32];

  const int z = blockIdx.z;
  const int g = z & 7;                       // fast index: g
  const int e = z >> 3;                      // slow index: expert
  const long mBase = (long)(g * EE + e) * 512 + blockIdx.y * 128;
  const int nBase = blockIdx.x * 128;

  const unsigned short* Ab = A + mBase * K;
  const unsigned short* Bb = Bt + ((long)e * N + nBase) * K;

  const int tid = threadIdx.x;
  const int lane = tid & 63;
  const int wave = tid >> 6;
  const int wm = wave & 1, wn = wave >> 1;   // 2x2 waves, each 64x64
  const int q = lane >> 4, mn = lane & 15;
  const int srow = lane >> 2, sb = lane & 3; // staging: 16 rows x 4 k-blocks per chunk

  f32x4 acc[4][4] = {};

  for (int k0 = 0; k0 < K; k0 += 32) {
    __syncthreads();
    // stage A and B tiles (128x32 each), 8 chunks of 1KB each, swizzled k-blocks:
    // LDS physical slot (row, b) holds global k-block (b ^ ((row>>1)&3))
#pragma unroll
    for (int j = 0; j < 2; ++j) {
      const int ca = wave + j * 4;           // chunk 0..7
      const int row = ca * 16 + srow;        // tile row 0..127
      const int kb = (sb ^ ((row >> 1) & 3)) * 8;
      gload_lds16(Ab + (long)row * K + k0 + kb, &As[ca * 512 + lane * 8]);
      gload_lds16(Bb + (long)row * K + k0 + kb, &Bs[ca * 512 + lane * 8]);
    }
    __syncthreads();

    bf16x8 af[4], bfr[4];
#pragma unroll
    for (int t = 0; t < 4; ++t) {
      const int m = wm * 64 + t * 16 + mn;
      af[t] = *(const bf16x8*)&As[m * 32 + ((q ^ ((m >> 1) & 3)) * 8)];
      const int n = wn * 64 + t * 16 + mn;
      bfr[t] = *(const bf16x8*)&Bs[n * 32 + ((q ^ ((n >> 1) & 3)) * 8)];
    }
#pragma unroll
    for (int mt = 0; mt < 4; ++mt)
#pragma unroll
      for (int nt = 0; nt < 4; ++nt)
        acc[mt][nt] = __builtin_amdgcn_mfma_f32_16x16x32_bf16(
            af[mt], bfr[nt], acc[mt][nt], 0, 0, 0);
  }

  // epilogue: C/D layout col = lane&15, row = (lane>>4)*4 + r  [m89/m91-verified]
#pragma unroll
  for (int nt = 0; nt < 4; ++nt) {
    const int n = nBase + wn * 64 + nt * 16 + mn;
    const float bv = bias[(long)e * N + n];
#pragma unroll
    for (int mt = 0; mt < 4; ++mt) {
#pragma unroll
      for (int r = 0; r < 4; ++r) {
        const long m = mBase + wm * 64 + mt * 16 + q * 4 + r;
        float v = acc[mt][nt][r] + bv;
        if (GELU) {
          v = 0.5f * v * (1.0f + erff(v * 0.70710678118654752f));
          ((unsigned short*)Out)[m * N + n] = f2bf(v);
        } else {
          ((float*)Out)[m * N + n] = v;
        }
      }
    }
  }
}

extern "C" void kernel_launch(void* const* d_in, const int* in_sizes, int n_in,
                              void* d_out, int out_size, void* d_ws, size_t ws_size,
                              hipStream_t stream) {
  const float* x  = (const float*)d_in[0];  // (G,E,C,H)
  const float* wi = (const float*)d_in[1];  // (E,H,F)
  const float* bi = (const float*)d_in[2];  // (E,F)
  const float* wo = (const float*)d_in[3];  // (E,F,H)
  const float* bo = (const float*)d_in[4];  // (E,H)
  float* out = (float*)d_out;               // (G,E,C,H) fp32

  // workspace layout (stream-ordered reuse of wt):
  //   xb: bf16 inputs            64 MiB @ 0
  //   yb: bf16 gelu intermediate 256 MiB @ 64 MiB
  //   wt: bf16 transposed weight 64 MiB @ 320 MiB (wi_t then wo_t)
  char* ws = (char*)d_ws;
  unsigned short* xb = (unsigned short*)ws;
  unsigned short* yb = (unsigned short*)(ws + (size_t)64 * 1024 * 1024);
  unsigned short* wt = (unsigned short*)(ws + (size_t)320 * 1024 * 1024);

  // 1) inputs fp32 -> bf16 (33,554,432 elems / 4 per thread / 256 per block)
  convert_bf16_kernel<<<32768, 256, 0, stream>>>((const float4*)x, (ushort4*)xb);

  // 2) wi (E,H,F) -> wi_t (E,F,H) bf16
  transpose_bf16<<<dim3(FF / 64, HH / 64, EE), 256, 0, stream>>>(wi, wt, HH, FF);

  // 3) GEMM1 + exact GELU: yb = gelu(xb @ wi_e + bi)  [K=1024, N=4096]
  ffn_gemm<1><<<dim3(FF / 128, 4, GG * EE), 256, 0, stream>>>(xb, wt, bi, yb, HH, FF);

  // 4) wo (E,F,H) -> wo_t (E,H,F) bf16 (overwrites wt; same stream => ordered)
  transpose_bf16<<<dim3(HH / 64, FF / 64, EE), 256, 0, stream>>>(wo, wt, FF, HH);

  // 5) GEMM2: out = yb @ wo_e + bo  [K=4096, N=1024], fp32 store
  ffn_gemm<0><<<dim3(HH / 128, 4, GG * EE), 256, 0, stream>>>(yb, wt, bo, out, FF, HH);
}

// Round 3
// 1125.222 us; speedup vs baseline: 1.2367x; 1.0631x over previous
//
#include <hip/hip_runtime.h>
#include <hip/hip_bf16.h>
#include <math.h>

// Problem dims (fixed by reference): G=8, E=8, C=512, H=1024, F=4096
#define GG 8
#define EE 8
#define CC 512
#define HH 1024
#define FF 4096

typedef __attribute__((ext_vector_type(8))) short bf16x8;   // 8 bf16 = 4 VGPRs
typedef __attribute__((ext_vector_type(4))) float f32x4;

__device__ __forceinline__ unsigned short f2bf(float f) {
  unsigned int u = __float_as_uint(f);
  u += 0x7FFFu + ((u >> 16) & 1u);   // RTNE
  return (unsigned short)(u >> 16);
}

__device__ __forceinline__ void gload_lds16(const void* g, void* l) {
  // async global->LDS, 16B/lane; LDS dest is wave-uniform base + lane*16
  __builtin_amdgcn_global_load_lds((__attribute__((address_space(1))) void*)g,
                                   (__attribute__((address_space(3))) void*)l,
                                   16, 0, 0);
}

// fast GELU: x * sigmoid(1.5957691x + 0.071354816x^3); |err vs exact| < ~1e-3,
// well under threshold and comparable to the bf16 rounding of yb.
__device__ __forceinline__ float fast_gelu(float x) {
  const float u = x * (1.5957691216057308f + 0.0713548162726009f * x * x);
  return x / (1.0f + __expf(-u));
}

// ---------------- fp32 -> bf16 straight conversion (vectorized) ----------------
__global__ void convert_bf16_kernel(const float4* __restrict__ in,
                                    ushort4* __restrict__ out) {
  const int i = blockIdx.x * blockDim.x + threadIdx.x;
  const float4 v = in[i];
  ushort4 o;
  o.x = f2bf(v.x); o.y = f2bf(v.y); o.z = f2bf(v.z); o.w = f2bf(v.w);
  out[i] = o;
}

// ---------------- fp32 (R x C) -> bf16 (C x R) transpose, per blockIdx.z slab ----------------
__global__ void transpose_bf16(const float* __restrict__ in,
                               unsigned short* __restrict__ out,
                               int R, int C) {
  __shared__ float tile[64][65];                 // +1 pad breaks bank conflicts
  const long ebase = (long)blockIdx.z * R * C;
  const int r0 = blockIdx.y * 64, c0 = blockIdx.x * 64;
  const int t = threadIdx.x;
  const int lr = t >> 4;            // 0..15
  const int lc = (t & 15) * 4;      // 0,4,...,60
#pragma unroll
  for (int p = 0; p < 4; ++p) {
    const int r = lr + p * 16;
    const float4 v = *(const float4*)(in + ebase + (long)(r0 + r) * C + c0 + lc);
    tile[r][lc + 0] = v.x; tile[r][lc + 1] = v.y;
    tile[r][lc + 2] = v.z; tile[r][lc + 3] = v.w;
  }
  __syncthreads();
#pragma unroll
  for (int p = 0; p < 4; ++p) {
    const int c = lr + p * 16;      // output row (original col)
    ushort4 o;
    o.x = f2bf(tile[lc + 0][c]);
    o.y = f2bf(tile[lc + 1][c]);
    o.z = f2bf(tile[lc + 2][c]);
    o.w = f2bf(tile[lc + 3][c]);
    *(ushort4*)(out + ebase + (long)(c0 + c) * R + r0 + lc) = o;
  }
}

// ---------------- bf16 GEMM: (rows x K) @ (N x K)^T, 128x128 tile, BK=32 ----------------
// blockIdx.z encodes (g,e) as z = e*8 + g  =>  consecutive blocks share the same
// expert's weight panel B_e (8 MiB) -> L2/LLC-resident during that expert's window.
// A rows for (g,e) live at linear slab (g*8+e)*512 (memory layout is (G,E,C,H)).
// GELU=1: fast-exact gelu epilogue, bf16 store via LDS (coalesced 128B rows).
// GELU=0: fp32 direct store (already 64B-coalesced per 16-lane group).
template <int GELU>
__global__ __launch_bounds__(256, 2)
void ffn_gemm(const unsigned short* __restrict__ A,   // (64*512) x K bf16
              const unsigned short* __restrict__ Bt,  // E x N x K bf16
              const float* __restrict__ bias,         // E x N fp32
              void* __restrict__ Out,                 // (64*512) x N
              int K, int N) {
  // As/Bs for the K-loop; ep aliases them for the GELU epilogue (after a barrier).
  __shared__ __align__(16) union SMem {
    struct { unsigned short As[128 * 32]; unsigned short Bs[128 * 32]; } s;
    unsigned short ep[4 * 32 * 68];   // 4 waves x (32 rows x 68-stride bf16)
  } smem;
  unsigned short* As = smem.s.As;
  unsigned short* Bs = smem.s.Bs;

  const int z = blockIdx.z;
  const int g = z & 7;                       // fast index: g
  const int e = z >> 3;                      // slow index: expert
  const long mBase = (long)(g * EE + e) * 512 + blockIdx.y * 128;
  const int nBase = blockIdx.x * 128;

  const unsigned short* Ab = A + mBase * K;
  const unsigned short* Bb = Bt + ((long)e * N + nBase) * K;

  const int tid = threadIdx.x;
  const int lane = tid & 63;
  const int wave = tid >> 6;
  const int wm = wave & 1, wn = wave >> 1;   // 2x2 waves, each 64x64
  const int q = lane >> 4, mn = lane & 15;
  const int srow = lane >> 2, sb = lane & 3; // staging: 16 rows x 4 k-blocks per chunk

  f32x4 acc[4][4] = {};

  for (int k0 = 0; k0 < K; k0 += 32) {
    __syncthreads();
    // stage A and B tiles (128x32 each), 8 chunks of 1KB each, swizzled k-blocks:
    // LDS physical slot (row, b) holds global k-block (b ^ ((row>>1)&3))
#pragma unroll
    for (int j = 0; j < 2; ++j) {
      const int ca = wave + j * 4;           // chunk 0..7
      const int row = ca * 16 + srow;        // tile row 0..127
      const int kb = (sb ^ ((row >> 1) & 3)) * 8;
      gload_lds16(Ab + (long)row * K + k0 + kb, &As[ca * 512 + lane * 8]);
      gload_lds16(Bb + (long)row * K + k0 + kb, &Bs[ca * 512 + lane * 8]);
    }
    __syncthreads();

    bf16x8 af[4], bfr[4];
#pragma unroll
    for (int t = 0; t < 4; ++t) {
      const int m = wm * 64 + t * 16 + mn;
      af[t] = *(const bf16x8*)&As[m * 32 + ((q ^ ((m >> 1) & 3)) * 8)];
      const int n = wn * 64 + t * 16 + mn;
      bfr[t] = *(const bf16x8*)&Bs[n * 32 + ((q ^ ((n >> 1) & 3)) * 8)];
    }
#pragma unroll
    for (int mt = 0; mt < 4; ++mt)
#pragma unroll
      for (int nt = 0; nt < 4; ++nt)
        acc[mt][nt] = __builtin_amdgcn_mfma_f32_16x16x32_bf16(
            af[mt], bfr[nt], acc[mt][nt], 0, 0, 0);
  }

  // C/D layout: col = lane&15, row = (lane>>4)*4 + r  [m89/m91-verified]
  if (GELU) {
    // gelu -> bf16 -> LDS (per-wave 32x68-stride region) -> coalesced 8B stores.
    __syncthreads();   // other waves may still be reading As/Bs (ep aliases them)
    unsigned short* ep = &smem.ep[wave * (32 * 68)];
    unsigned short* outp = (unsigned short*)Out;
#pragma unroll
    for (int p2 = 0; p2 < 2; ++p2) {
      // write phase: rows [p2*32, p2*32+32) of this wave's 64x64 tile
#pragma unroll
      for (int mt = 2 * p2; mt < 2 * p2 + 2; ++mt) {
#pragma unroll
        for (int nt = 0; nt < 4; ++nt) {
          const int n = nBase + wn * 64 + nt * 16 + mn;
          const float bv = bias[(long)e * N + n];
#pragma unroll
          for (int r = 0; r < 4; ++r) {
            const int lr = (mt - 2 * p2) * 16 + q * 4 + r;
            const float v = fast_gelu(acc[mt][nt][r] + bv);
            ep[lr * 68 + nt * 16 + mn] = f2bf(v);
          }
        }
      }
      // read phase: 8B/lane, 16 lanes cover one 128B row segment
      const int c4 = (lane & 15) * 4;            // col in ushorts
#pragma unroll
      for (int i = 0; i < 8; ++i) {
        const int lr2 = i * 4 + (lane >> 4);
        const ushort4 v = *(const ushort4*)&ep[lr2 * 68 + c4];
        const long m = mBase + wm * 64 + p2 * 32 + lr2;
        *(ushort4*)&outp[m * N + nBase + wn * 64 + c4] = v;
      }
    }
  } else {
#pragma unroll
    for (int nt = 0; nt < 4; ++nt) {
      const int n = nBase + wn * 64 + nt * 16 + mn;
      const float bv = bias[(long)e * N + n];
#pragma unroll
      for (int mt = 0; mt < 4; ++mt) {
#pragma unroll
        for (int r = 0; r < 4; ++r) {
          const long m = mBase + wm * 64 + mt * 16 + q * 4 + r;
          ((float*)Out)[m * N + n] = acc[mt][nt][r] + bv;
        }
      }
    }
  }
}

extern "C" void kernel_launch(void* const* d_in, const int* in_sizes, int n_in,
                              void* d_out, int out_size, void* d_ws, size_t ws_size,
                              hipStream_t stream) {
  const float* x  = (const float*)d_in[0];  // (G,E,C,H)
  const float* wi = (const float*)d_in[1];  // (E,H,F)
  const float* bi = (const float*)d_in[2];  // (E,F)
  const float* wo = (const float*)d_in[3];  // (E,F,H)
  const float* bo = (const float*)d_in[4];  // (E,H)
  float* out = (float*)d_out;               // (G,E,C,H) fp32

  // workspace layout (stream-ordered reuse of wt):
  //   xb: bf16 inputs            64 MiB @ 0
  //   yb: bf16 gelu intermediate 256 MiB @ 64 MiB
  //   wt: bf16 transposed weight 64 MiB @ 320 MiB (wi_t then wo_t)
  char* ws = (char*)d_ws;
  unsigned short* xb = (unsigned short*)ws;
  unsigned short* yb = (unsigned short*)(ws + (size_t)64 * 1024 * 1024);
  unsigned short* wt = (unsigned short*)(ws + (size_t)320 * 1024 * 1024);

  // 1) inputs fp32 -> bf16
  convert_bf16_kernel<<<32768, 256, 0, stream>>>((const float4*)x, (ushort4*)xb);

  // 2) wi (E,H,F) -> wi_t (E,F,H) bf16
  transpose_bf16<<<dim3(FF / 64, HH / 64, EE), 256, 0, stream>>>(wi, wt, HH, FF);

  // 3) GEMM1 + gelu: yb = gelu(xb @ wi_e + bi)  [K=1024, N=4096]
  ffn_gemm<1><<<dim3(FF / 128, 4, GG * EE), 256, 0, stream>>>(xb, wt, bi, yb, HH, FF);

  // 4) wo (E,F,H) -> wo_t (E,H,F) bf16 (overwrites wt; same stream => ordered)
  transpose_bf16<<<dim3(HH / 64, FF / 64, EE), 256, 0, stream>>>(wo, wt, FF, HH);

  // 5) GEMM2: out = yb @ wo_e + bo  [K=4096, N=1024], fp32 store
  ffn_gemm<0><<<dim3(HH / 128, 4, GG * EE), 256, 0, stream>>>(yb, wt, bo, out, FF, HH);
}